// Round 17
// baseline (314.399 us; speedup 1.0000x reference)
//
#include <hip/hip_runtime.h>

#define T_STEPS 15
#define ROWS_PER_BLOCK 128
#define B_TOTAL 262144
#define LOG2E 1.4426950408889634f

typedef _Float16 half8 __attribute__((ext_vector_type(8)));
typedef _Float16 half4 __attribute__((ext_vector_type(4)));
typedef __fp16   fp16x2 __attribute__((ext_vector_type(2)));   // cvt_pkrtz return type
typedef float f32x4 __attribute__((ext_vector_type(4)));

// Intrinsic MFMA: compiler handles D/A/B register constraints and MFMA
// hazards (rounds 14/16 proved inline-asm MFMA corrupts at (256,3) where the
// allocator reuses MFMA-source regs — opaque to the hazard recognizer).
#define MFMA_INIT(acc, a, b, cz) \
    (acc) = __builtin_amdgcn_mfma_f32_16x16x32_f16((a), (b), (cz), 0, 0, 0)
#define MFMA_ACC(acc, a, b) \
    (acc) = __builtin_amdgcn_mfma_f32_16x16x32_f16((a), (b), (acc), 0, 0, 0)

#define SB() __builtin_amdgcn_sched_barrier(0)

// Swizzled element index into a [rows][64] fp16 LDS tile (T2 pattern).
__device__ __forceinline__ int swz(int row, int e) {
    return (row * 64 + e) ^ ((row & 7) << 3);
}

// One gate evaluation (5 trans ops) for (stream SG, quadrant TQ, C-reg RG).
#define GEVAL(SG, RG, TQ, XT) do { \
    float pr = accr[SG][TQ][RG] + __builtin_fmaf(XT, wihr[TQ], sr[TQ]); \
    float er = __builtin_amdgcn_exp2f(-pr); \
    float rg_ = __builtin_amdgcn_rcpf(1.0f + er); \
    float pz = accz[SG][TQ][RG] + __builtin_fmaf(XT, wihz[TQ], sz[TQ]); \
    float ez = __builtin_amdgcn_exp2f(-pz); \
    float na = __builtin_fmaf(rg_, accn[SG][TQ][RG], \
                __builtin_fmaf(rg_, seedn[TQ], \
                 __builtin_fmaf(XT, wihn[TQ], bihn[TQ]))); \
    float en = __builtin_amdgcn_exp2f(-na); \
    float A_ = 1.0f + en; \
    float C_ = 1.0f + ez; \
    float R_ = __builtin_amdgcn_rcpf(A_ * C_); \
    float P_ = __builtin_fmaf(-en, ez, ez); \
    float hn = __builtin_fmaf(h[SG][TQ][RG], A_, P_) * R_; \
    h[SG][TQ][RG] = hn; \
    hnv[TQ] = hn; \
} while (0)

#define PACKWRITE(SG, RG) do { \
    fp16x2 h01 = __builtin_amdgcn_cvt_pkrtz(hnv[0], hnv[1]); \
    fp16x2 h23 = __builtin_amdgcn_cvt_pkrtz(hnv[2], hnv[3]); \
    half4 vh; \
    vh[0] = (_Float16)h01[0]; vh[1] = (_Float16)h01[1]; \
    vh[2] = (_Float16)h23[0]; vh[3] = (_Float16)h23[1]; \
    *(half4*)wr[SG][RG] = vh; \
} while (0)

// Load the 6 B-fragments (r,z,n x 2 k-steps) for quadrant KK.
#define LD6(buf, KK) do { \
    buf[0] = *(const half8*)(bp0 + (KK) * 2048); \
    buf[1] = *(const half8*)(bp1 + (KK) * 2048); \
    buf[2] = *(const half8*)(bp0 + (4 + (KK)) * 2048); \
    buf[3] = *(const half8*)(bp1 + (4 + (KK)) * 2048); \
    buf[4] = *(const half8*)(bp0 + (8 + (KK)) * 2048); \
    buf[5] = *(const half8*)(bp1 + (8 + (KK)) * 2048); \
} while (0)

// Rotated fused chunk, 2-1-1 form: PREF | G0,G1 | INITx3 | G2 | ACCx3 |
// G3+PACK. Two leading evals cover the ds_read->INIT latency; one eval
// separates INIT->ACC. SB() pins the interleave.
#define CHUNK(SM, SG, K, BCUR, PREF) do { \
    float hnv[4]; \
    float XT = (float)xcur[K]; \
    PREF; \
    SB(); \
    GEVAL(SG, K, 0, XT); GEVAL(SG, K, 1, XT); \
    SB(); \
    MFMA_INIT(accr[SM][K], A0, BCUR[0], zero4); \
    MFMA_INIT(accz[SM][K], A0, BCUR[2], zero4); \
    MFMA_INIT(accn[SM][K], A0, BCUR[4], zero4); \
    SB(); \
    GEVAL(SG, K, 2, XT); \
    SB(); \
    MFMA_ACC(accr[SM][K], A1, BCUR[1]); \
    MFMA_ACC(accz[SM][K], A1, BCUR[3]); \
    MFMA_ACC(accn[SM][K], A1, BCUR[5]); \
    SB(); \
    GEVAL(SG, K, 3, XT); \
    PACKWRITE(SG, K); \
    SB(); \
} while (0)

// Fused phase: K=64 matvec for stream SM overlapped with the gate pass for
// stream SG (x values in xcur, preloaded LAST phase). First action: issue
// the NEXT phase's x read into xnext (~full phase of cover).
#define FUSED(SM, SG, XNS, XNT) do { \
    int ofA = bytesS0, ofB = bytesS1; \
    asm volatile("" : "+v"(ofA), "+v"(ofB)); \
    const char* bp0 = wbase + ofA; \
    const char* bp1 = wbase + ofB; \
    xnext = *(const half4*)&xlds[(XNT) * ROWS_PER_BLOCK + wave * 32 + (XNS) * 16 + g4 * 4]; \
    half8 Bf0[6], Bf1[6]; \
    LD6(Bf0, 0); \
    half8 A0 = *(const half8*)((SM) ? aB0 : aA0); \
    half8 A1 = *(const half8*)((SM) ? aB1 : aA1); \
    CHUNK(SM, SG, 0, Bf0, LD6(Bf1, 1)); \
    CHUNK(SM, SG, 1, Bf1, LD6(Bf0, 2)); \
    CHUNK(SM, SG, 2, Bf0, LD6(Bf1, 3)); \
    CHUNK(SM, SG, 3, Bf1, (void)0); \
} while (0)

// Plain gate pass (pipeline prologue/epilogue), x from xcur.
#define GATES_PLAIN(SG) do { \
    _Pragma("unroll") \
    for (int rg2 = 0; rg2 < 4; ++rg2) { \
        float hnv[4]; \
        float XT = (float)xcur[rg2]; \
        GEVAL(SG, rg2, 0, XT); GEVAL(SG, rg2, 1, XT); \
        GEVAL(SG, rg2, 2, XT); GEVAL(SG, rg2, 3, XT); \
        PACKWRITE(SG, rg2); \
    } \
} while (0)

__global__ __launch_bounds__(256, 3) void gru_mfma_kernel(
    const float* __restrict__ x,     // (B,15)
    const float* __restrict__ W_ih,  // (192,1)
    const float* __restrict__ W_hh,  // (192,64)
    const float* __restrict__ b_ih,  // (192,)
    const float* __restrict__ b_hh,  // (192,)
    const float* __restrict__ W_fc,  // (2,64)
    const float* __restrict__ b_fc,  // (2,)
    float* __restrict__ out)         // (B,2)
{
    __shared__ _Float16 wlds[192 * 64];                  // 24576 B, exp2-prescaled W_hh^T
    __shared__ _Float16 xlds[T_STEPS * ROWS_PER_BLOCK];  // 3840 B, f16 x, [t][row]
    __shared__ _Float16 hst[8][16 * 64];                 // [wave*2+stream], 16384 B
    // total 44800 B -> 3 blocks/CU (r4 proved 3 fit at 45056 with (256,3))

    const int tid  = threadIdx.x;
    const int wave = tid >> 6;
    const int lane = tid & 63;
    const int c    = lane & 15;   // N-col / A-row index
    const int g4   = lane >> 4;   // k-slot group / C-row group
    const int r0   = blockIdx.x * ROWS_PER_BLOCK;

    // ---- stage B = W_hh^T, k-permuted by invs(s)=(s&3)*16+(s>>2), exp2-scaled ----
    for (int idx = tid; idx < 192 * 64; idx += 256) {
        int n = idx >> 6, s = idx & 63;
        int korig = (s & 3) * 16 + (s >> 2);
        float scale = (n < 128) ? LOG2E : (2.0f * LOG2E);
        wlds[swz(n, s)] = (_Float16)(W_hh[n * 64 + korig] * scale);
    }
    // x transposed + f16: xlds[t*128 + row]. x only enters as x*W_ih
    // (|W_ih|<=0.125) -> f16 rounding adds <=~2e-5 to gate preacts.
    for (int idx = tid; idx < ROWS_PER_BLOCK * T_STEPS; idx += 256) {
        int row = idx / T_STEPS, t = idx - row * T_STEPS;
        xlds[t * ROWS_PER_BLOCK + row] = (_Float16)x[r0 * T_STEPS + idx];
    }
    __syncthreads();

    // ---- per-lane gate constants (jn = tq*16 + c), exp2-prescaled ----
    float wihr[4], wihz[4], wihn[4], sr[4], sz[4], seedn[4], bihn[4];
#pragma unroll
    for (int tq = 0; tq < 4; ++tq) {
        int jn = tq * 16 + c;
        wihr[tq]  = W_ih[jn] * LOG2E;
        wihz[tq]  = W_ih[64 + jn] * LOG2E;
        wihn[tq]  = W_ih[128 + jn] * (2.0f * LOG2E);
        sr[tq]    = (b_ih[jn] + b_hh[jn]) * LOG2E;
        sz[tq]    = (b_ih[64 + jn] + b_hh[64 + jn]) * LOG2E;
        seedn[tq] = b_hh[128 + jn] * (2.0f * LOG2E);  // stays inside r*(.) per reference
        bihn[tq]  = b_ih[128 + jn] * (2.0f * LOG2E);
    }

    // ---- loop-invariant LDS offsets (swizzle folded) ----
    const int eS0 = c * 64 + (((g4 * 8) + 0)  ^ ((c & 7) << 3));  // k-step 0
    const int eS1 = c * 64 + (((g4 * 8) + 32) ^ ((c & 7) << 3));  // k-step 1
    const int bytesS0 = eS0 * 2;
    const int bytesS1 = eS1 * 2;
    const _Float16* aA0 = &hst[wave * 2 + 0][eS0];
    const _Float16* aA1 = &hst[wave * 2 + 0][eS1];
    const _Float16* aB0 = &hst[wave * 2 + 1][eS0];
    const _Float16* aB1 = &hst[wave * 2 + 1][eS1];
    _Float16* wr[2][4];
#pragma unroll
    for (int s = 0; s < 2; ++s)
#pragma unroll
        for (int reg = 0; reg < 4; ++reg) {
            int row = g4 * 4 + reg;
            wr[s][reg] = &hst[wave * 2 + s][row * 64 + ((c * 4) ^ ((row & 7) << 3))];
        }

    const f32x4 zero4 = (f32x4){0.0f, 0.0f, 0.0f, 0.0f};

    f32x4 accr[2][4], accz[2][4], accn[2][4];   // zero needed for the t=0 gates
#pragma unroll
    for (int s = 0; s < 2; ++s)
#pragma unroll
        for (int tq = 0; tq < 4; ++tq) {
            accr[s][tq] = zero4;
            accz[s][tq] = zero4;
            accn[s][tq] = zero4;
        }

    float h[2][4][4];  // fp32 h, C layout per stream
#pragma unroll
    for (int s = 0; s < 2; ++s)
#pragma unroll
        for (int tq = 0; tq < 4; ++tq)
#pragma unroll
            for (int reg = 0; reg < 4; ++reg) h[s][tq][reg] = 0.0f;

    const char* wbase = (const char*)&wlds[0];

    // ---- software pipeline, chunk-fused, x preloaded one phase ahead:
    // P0: gA(0) | P1: F(MA(1) x gB(0)) | P_{2t}: F(MB(t) x gA(t)) |
    // P_{2t+1}: F(MA(t+1) x gB(t)) | P28: F(MB(14) x gA(14)) | P29: gB(14)
    half4 xcur, xnext;
    xcur  = *(const half4*)&xlds[0 * ROWS_PER_BLOCK + wave * 32 + 0 * 16 + g4 * 4];  // (A, t0)
    xnext = *(const half4*)&xlds[0 * ROWS_PER_BLOCK + wave * 32 + 1 * 16 + g4 * 4];  // (B, t0)
    GATES_PLAIN(0);                 // gates_A(0), acc=0 path
    xcur = xnext;
    FUSED(0, 1, 0, 1);              // MFMA_A(1) x gates_B(0); preload (A, t1)

#pragma unroll 1
    for (int t = 1; t < T_STEPS - 1; ++t) {
        xcur = xnext;
        FUSED(1, 0, 1, t);          // MFMA_B(t) x gates_A(t); preload (B, t)
        xcur = xnext;
        FUSED(0, 1, 0, t + 1);      // MFMA_A(t+1) x gates_B(t); preload (A, t+1)
    }

    xcur = xnext;
    FUSED(1, 0, 1, T_STEPS - 1);    // MFMA_B(14) x gates_A(14); preload (B, 14)
    xcur = xnext;
    GATES_PLAIN(1);                 // gates_B(14)

    // ---- FC head from exact fp32 h; launder pointers so W_fc/b_fc loads
    // can't be hoisted above the t-loop ----
    const float* wfc = W_fc;
    const float* bfc = b_fc;
    asm volatile("" : "+v"(wfc), "+v"(bfc));
    float wfc0[4], wfc1[4];
#pragma unroll
    for (int tq = 0; tq < 4; ++tq) {
        wfc0[tq] = wfc[tq * 16 + c];
        wfc1[tq] = wfc[64 + tq * 16 + c];
    }
#pragma unroll
    for (int s = 0; s < 2; ++s)
#pragma unroll
    for (int reg = 0; reg < 4; ++reg) {
        float s0 = 0.0f, s1 = 0.0f;
#pragma unroll
        for (int tq = 0; tq < 4; ++tq) {
            s0 = __builtin_fmaf(h[s][tq][reg], wfc0[tq], s0);
            s1 = __builtin_fmaf(h[s][tq][reg], wfc1[tq], s1);
        }
#pragma unroll
        for (int m = 1; m < 16; m <<= 1) {
            s0 += __shfl_xor(s0, m, 64);
            s1 += __shfl_xor(s1, m, 64);
        }
        if (c == 0) {
            int gr = r0 + wave * 32 + s * 16 + g4 * 4 + reg;
            out[gr * 2 + 0] = s0 + bfc[0];
            out[gr * 2 + 1] = s1 + bfc[1];
        }
    }
}

extern "C" void kernel_launch(void* const* d_in, const int* in_sizes, int n_in,
                              void* d_out, int out_size, void* d_ws, size_t ws_size,
                              hipStream_t stream) {
    const float* x    = (const float*)d_in[0];
    const float* W_ih = (const float*)d_in[1];
    const float* W_hh = (const float*)d_in[2];
    const float* b_ih = (const float*)d_in[3];
    const float* b_hh = (const float*)d_in[4];
    const float* W_fc = (const float*)d_in[5];
    const float* b_fc = (const float*)d_in[6];
    float* out = (float*)d_out;

    dim3 grid(B_TOTAL / ROWS_PER_BLOCK);
    dim3 block(256);
    gru_mfma_kernel<<<grid, block, 0, stream>>>(x, W_ih, W_hh, b_ih, b_hh, W_fc, b_fc, out);
}

// Round 18
// 199.155 us; speedup vs baseline: 1.5787x; 1.5787x over previous
//
#include <hip/hip_runtime.h>

#define T_STEPS 15
#define ROWS_PER_BLOCK 128
#define B_TOTAL 262144
#define LOG2E 1.4426950408889634f

typedef _Float16 half8 __attribute__((ext_vector_type(8)));
typedef _Float16 half4 __attribute__((ext_vector_type(4)));
typedef __fp16   fp16x2 __attribute__((ext_vector_type(2)));   // cvt_pkrtz return type
typedef float f32x4 __attribute__((ext_vector_type(4)));

// VGPR-form MFMA (gfx950 unified RF). INIT overwrites acc (C = shared zero
// tuple); "=&v" early-clobber so D can't alias C.
// NOTE: this asm form is validated ONLY at __launch_bounds__(256,2)'s
// register allocation (6 consecutive passing rounds). At (256,3) the tighter
// allocation exposes an MFMA source-overlap/WAR hazard (r14/r16 corruption)
// — do not change the launch bounds without switching to intrinsics.
#define MFMA_INIT(acc, a, b, cz) \
    asm("v_mfma_f32_16x16x32_f16 %0, %1, %2, %3" : "=&v"(acc) : "v"(a), "v"(b), "v"(cz))
#define MFMA_ACC(acc, a, b) \
    asm("v_mfma_f32_16x16x32_f16 %0, %1, %2, %0" : "+v"(acc) : "v"(a), "v"(b))

#define SB() __builtin_amdgcn_sched_barrier(0)

// Swizzled element index into a [rows][64] fp16 LDS tile (T2 pattern).
__device__ __forceinline__ int swz(int row, int e) {
    return (row * 64 + e) ^ ((row & 7) << 3);
}

// One gate evaluation (5 trans ops — algebraic minimum) for
// (stream SG, quadrant TQ, C-reg RG).
#define GEVAL(SG, RG, TQ, XT) do { \
    float pr = accr[SG][TQ][RG] + __builtin_fmaf(XT, wihr[TQ], sr[TQ]); \
    float er = __builtin_amdgcn_exp2f(-pr); \
    float rg_ = __builtin_amdgcn_rcpf(1.0f + er); \
    float pz = accz[SG][TQ][RG] + __builtin_fmaf(XT, wihz[TQ], sz[TQ]); \
    float ez = __builtin_amdgcn_exp2f(-pz); \
    float na = __builtin_fmaf(rg_, accn[SG][TQ][RG], \
                __builtin_fmaf(rg_, seedn[TQ], \
                 __builtin_fmaf(XT, wihn[TQ], bihn[TQ]))); \
    float en = __builtin_amdgcn_exp2f(-na); \
    float A_ = 1.0f + en; \
    float C_ = 1.0f + ez; \
    float R_ = __builtin_amdgcn_rcpf(A_ * C_); \
    float P_ = __builtin_fmaf(-en, ez, ez); \
    float hn = __builtin_fmaf(h[SG][TQ][RG], A_, P_) * R_; \
    h[SG][TQ][RG] = hn; \
    hnv[TQ] = hn; \
} while (0)

#define PACKWRITE(SG, RG) do { \
    fp16x2 h01 = __builtin_amdgcn_cvt_pkrtz(hnv[0], hnv[1]); \
    fp16x2 h23 = __builtin_amdgcn_cvt_pkrtz(hnv[2], hnv[3]); \
    half4 vh; \
    vh[0] = (_Float16)h01[0]; vh[1] = (_Float16)h01[1]; \
    vh[2] = (_Float16)h23[0]; vh[3] = (_Float16)h23[1]; \
    *(half4*)wr[SG][RG] = vh; \
} while (0)

// Load the 6 B-fragments (r,z,n x 2 k-steps) for quadrant KK.
#define LD6(buf, KK) do { \
    buf[0] = *(const half8*)(bp0 + (KK) * 2048); \
    buf[1] = *(const half8*)(bp1 + (KK) * 2048); \
    buf[2] = *(const half8*)(bp0 + (4 + (KK)) * 2048); \
    buf[3] = *(const half8*)(bp1 + (4 + (KK)) * 2048); \
    buf[4] = *(const half8*)(bp0 + (8 + (KK)) * 2048); \
    buf[5] = *(const half8*)(bp1 + (8 + (KK)) * 2048); \
} while (0)

// Rotated fused chunk, 2-1-1 form: PREF | G0,G1 | INITx3 | G2 | ACCx3 |
// G3+PACK. Two leading evals (zero memory deps — x is in regs) cover the
// ds_read->INIT latency; one eval separates INIT->ACC. SB() pins it.
#define CHUNK(SM, SG, K, BCUR, PREF) do { \
    float hnv[4]; \
    float XT = xcur[K]; \
    PREF; \
    SB(); \
    GEVAL(SG, K, 0, XT); GEVAL(SG, K, 1, XT); \
    SB(); \
    MFMA_INIT(accr[SM][K], A0, BCUR[0], zero4); \
    MFMA_INIT(accz[SM][K], A0, BCUR[2], zero4); \
    MFMA_INIT(accn[SM][K], A0, BCUR[4], zero4); \
    SB(); \
    GEVAL(SG, K, 2, XT); \
    SB(); \
    MFMA_ACC(accr[SM][K], A1, BCUR[1]); \
    MFMA_ACC(accz[SM][K], A1, BCUR[3]); \
    MFMA_ACC(accn[SM][K], A1, BCUR[5]); \
    SB(); \
    GEVAL(SG, K, 3, XT); \
    PACKWRITE(SG, K); \
    SB(); \
} while (0)

// Fused phase: K=64 matvec for stream SM overlapped with the gate pass for
// stream SG (x values in xcur, preloaded LAST phase). First action: issue
// the NEXT phase's x read into xnext (~full phase of cover).
#define FUSED(SM, SG, XNS, XNT) do { \
    int ofA = bytesS0, ofB = bytesS1; \
    asm volatile("" : "+v"(ofA), "+v"(ofB)); \
    const char* bp0 = wbase + ofA; \
    const char* bp1 = wbase + ofB; \
    xnext = *(const f32x4*)&xlds[(XNT) * ROWS_PER_BLOCK + wave * 32 + (XNS) * 16 + g4 * 4]; \
    half8 Bf0[6], Bf1[6]; \
    LD6(Bf0, 0); \
    half8 A0 = *(const half8*)((SM) ? aB0 : aA0); \
    half8 A1 = *(const half8*)((SM) ? aB1 : aA1); \
    CHUNK(SM, SG, 0, Bf0, LD6(Bf1, 1)); \
    CHUNK(SM, SG, 1, Bf1, LD6(Bf0, 2)); \
    CHUNK(SM, SG, 2, Bf0, LD6(Bf1, 3)); \
    CHUNK(SM, SG, 3, Bf1, (void)0); \
} while (0)

// Plain gate pass (pipeline prologue/epilogue), x from xcur.
#define GATES_PLAIN(SG) do { \
    _Pragma("unroll") \
    for (int rg2 = 0; rg2 < 4; ++rg2) { \
        float hnv[4]; \
        float XT = xcur[rg2]; \
        GEVAL(SG, rg2, 0, XT); GEVAL(SG, rg2, 1, XT); \
        GEVAL(SG, rg2, 2, XT); GEVAL(SG, rg2, 3, XT); \
        PACKWRITE(SG, rg2); \
    } \
} while (0)

__global__ __launch_bounds__(256, 2) void gru_mfma_kernel(
    const float* __restrict__ x,     // (B,15)
    const float* __restrict__ W_ih,  // (192,1)
    const float* __restrict__ W_hh,  // (192,64)
    const float* __restrict__ b_ih,  // (192,)
    const float* __restrict__ b_hh,  // (192,)
    const float* __restrict__ W_fc,  // (2,64)
    const float* __restrict__ b_fc,  // (2,)
    float* __restrict__ out)         // (B,2)
{
    __shared__ _Float16 wlds[192 * 64];                 // 24576 B, exp2-prescaled W_hh^T
    __shared__ float    xlds[T_STEPS * ROWS_PER_BLOCK]; // 7680 B, [t][row]
    __shared__ _Float16 hst[8][16 * 64];                // [wave*2+stream], 16384 B

    const int tid  = threadIdx.x;
    const int wave = tid >> 6;
    const int lane = tid & 63;
    const int c    = lane & 15;   // N-col / A-row index
    const int g4   = lane >> 4;   // k-slot group / C-row group
    const int r0   = blockIdx.x * ROWS_PER_BLOCK;

    // ---- stage B = W_hh^T, k-permuted by invs(s)=(s&3)*16+(s>>2), exp2-scaled ----
    for (int idx = tid; idx < 192 * 64; idx += 256) {
        int n = idx >> 6, s = idx & 63;
        int korig = (s & 3) * 16 + (s >> 2);
        float scale = (n < 128) ? LOG2E : (2.0f * LOG2E);
        wlds[swz(n, s)] = (_Float16)(W_hh[n * 64 + korig] * scale);
    }
    // x transposed: xlds[t*128 + row]
    for (int idx = tid; idx < ROWS_PER_BLOCK * T_STEPS; idx += 256) {
        int row = idx / T_STEPS, t = idx - row * T_STEPS;
        xlds[t * ROWS_PER_BLOCK + row] = x[r0 * T_STEPS + idx];
    }
    __syncthreads();

    // ---- per-lane gate constants (jn = tq*16 + c), exp2-prescaled ----
    float wihr[4], wihz[4], wihn[4], sr[4], sz[4], seedn[4], bihn[4];
#pragma unroll
    for (int tq = 0; tq < 4; ++tq) {
        int jn = tq * 16 + c;
        wihr[tq]  = W_ih[jn] * LOG2E;
        wihz[tq]  = W_ih[64 + jn] * LOG2E;
        wihn[tq]  = W_ih[128 + jn] * (2.0f * LOG2E);
        sr[tq]    = (b_ih[jn] + b_hh[jn]) * LOG2E;
        sz[tq]    = (b_ih[64 + jn] + b_hh[64 + jn]) * LOG2E;
        seedn[tq] = b_hh[128 + jn] * (2.0f * LOG2E);  // stays inside r*(.) per reference
        bihn[tq]  = b_ih[128 + jn] * (2.0f * LOG2E);
    }

    // ---- loop-invariant LDS offsets (swizzle folded) ----
    const int eS0 = c * 64 + (((g4 * 8) + 0)  ^ ((c & 7) << 3));  // k-step 0
    const int eS1 = c * 64 + (((g4 * 8) + 32) ^ ((c & 7) << 3));  // k-step 1
    const int bytesS0 = eS0 * 2;
    const int bytesS1 = eS1 * 2;
    const _Float16* aA0 = &hst[wave * 2 + 0][eS0];
    const _Float16* aA1 = &hst[wave * 2 + 0][eS1];
    const _Float16* aB0 = &hst[wave * 2 + 1][eS0];
    const _Float16* aB1 = &hst[wave * 2 + 1][eS1];
    _Float16* wr[2][4];
#pragma unroll
    for (int s = 0; s < 2; ++s)
#pragma unroll
        for (int reg = 0; reg < 4; ++reg) {
            int row = g4 * 4 + reg;
            wr[s][reg] = &hst[wave * 2 + s][row * 64 + ((c * 4) ^ ((row & 7) << 3))];
        }

    const f32x4 zero4 = (f32x4){0.0f, 0.0f, 0.0f, 0.0f};

    f32x4 accr[2][4], accz[2][4], accn[2][4];   // zero needed for the t=0 gates
#pragma unroll
    for (int s = 0; s < 2; ++s)
#pragma unroll
        for (int tq = 0; tq < 4; ++tq) {
            accr[s][tq] = zero4;
            accz[s][tq] = zero4;
            accn[s][tq] = zero4;
        }

    float h[2][4][4];  // fp32 h, C layout per stream
#pragma unroll
    for (int s = 0; s < 2; ++s)
#pragma unroll
        for (int tq = 0; tq < 4; ++tq)
#pragma unroll
            for (int reg = 0; reg < 4; ++reg) h[s][tq][reg] = 0.0f;

    const char* wbase = (const char*)&wlds[0];

    // ---- software pipeline, chunk-fused, x preloaded one phase ahead:
    // P0: gA(0) | P1: F(MA(1) x gB(0)) | P_{2t}: F(MB(t) x gA(t)) |
    // P_{2t+1}: F(MA(t+1) x gB(t)) | P28: F(MB(14) x gA(14)) | P29: gB(14)
    f32x4 xcur, xnext;
    xcur  = *(const f32x4*)&xlds[0 * ROWS_PER_BLOCK + wave * 32 + 0 * 16 + g4 * 4];  // (A, t0)
    xnext = *(const f32x4*)&xlds[0 * ROWS_PER_BLOCK + wave * 32 + 1 * 16 + g4 * 4];  // (B, t0)
    GATES_PLAIN(0);                 // gates_A(0), acc=0 path
    xcur = xnext;
    FUSED(0, 1, 0, 1);              // MFMA_A(1) x gates_B(0); preload (A, t1)

#pragma unroll 1
    for (int t = 1; t < T_STEPS - 1; ++t) {
        xcur = xnext;
        FUSED(1, 0, 1, t);          // MFMA_B(t) x gates_A(t); preload (B, t)
        xcur = xnext;
        FUSED(0, 1, 0, t + 1);      // MFMA_A(t+1) x gates_B(t); preload (A, t+1)
    }

    xcur = xnext;
    FUSED(1, 0, 1, T_STEPS - 1);    // MFMA_B(14) x gates_A(14); preload (B, 14)
    SB(); asm volatile("s_nop 7"); SB();    // insurance pad
    xcur = xnext;
    GATES_PLAIN(1);                 // gates_B(14)

    // ---- FC head from exact fp32 h; launder pointers so W_fc/b_fc loads
    // can't be hoisted above the t-loop ----
    const float* wfc = W_fc;
    const float* bfc = b_fc;
    asm volatile("" : "+v"(wfc), "+v"(bfc));
    float wfc0[4], wfc1[4];
#pragma unroll
    for (int tq = 0; tq < 4; ++tq) {
        wfc0[tq] = wfc[tq * 16 + c];
        wfc1[tq] = wfc[64 + tq * 16 + c];
    }
#pragma unroll
    for (int s = 0; s < 2; ++s)
#pragma unroll
    for (int reg = 0; reg < 4; ++reg) {
        float s0 = 0.0f, s1 = 0.0f;
#pragma unroll
        for (int tq = 0; tq < 4; ++tq) {
            s0 = __builtin_fmaf(h[s][tq][reg], wfc0[tq], s0);
            s1 = __builtin_fmaf(h[s][tq][reg], wfc1[tq], s1);
        }
#pragma unroll
        for (int m = 1; m < 16; m <<= 1) {
            s0 += __shfl_xor(s0, m, 64);
            s1 += __shfl_xor(s1, m, 64);
        }
        if (c == 0) {
            int gr = r0 + wave * 32 + s * 16 + g4 * 4 + reg;
            out[gr * 2 + 0] = s0 + bfc[0];
            out[gr * 2 + 1] = s1 + bfc[1];
        }
    }
}

extern "C" void kernel_launch(void* const* d_in, const int* in_sizes, int n_in,
                              void* d_out, int out_size, void* d_ws, size_t ws_size,
                              hipStream_t stream) {
    const float* x    = (const float*)d_in[0];
    const float* W_ih = (const float*)d_in[1];
    const float* W_hh = (const float*)d_in[2];
    const float* b_ih = (const float*)d_in[3];
    const float* b_hh = (const float*)d_in[4];
    const float* W_fc = (const float*)d_in[5];
    const float* b_fc = (const float*)d_in[6];
    float* out = (float*)d_out;

    dim3 grid(B_TOTAL / ROWS_PER_BLOCK);
    dim3 block(256);
    gru_mfma_kernel<<<grid, block, 0, stream>>>(x, W_ih, W_hh, b_ih, b_hh, W_fc, b_fc, out);
}